// Round 1
// baseline (332.970 us; speedup 1.0000x reference)
//
#include <hip/hip_runtime.h>
#include <math.h>

// FilterDetection: score threshold + morphological opening (erode 4x4 then
// dilate 4x4) on 32x1024x1024 f32 mask.
//
// Window geometry (from lax.reduce_window padding in the reference):
//   erode : offsets [-2..+1] both axes, OOB = +inf
//   dilate: offsets [-1..+2] both axes, OOB = -inf
// Fully fused: each block computes a 64x64 output tile from a 70x70
// thresholded input tile in LDS (halo = 3 each side). Separable min/max
// passes ping-pong between two LDS buffers.

#define H 1024
#define W 1024
#define TX 64
#define TY 64
#define TR (TY + 6)   // 70 rows in LDS tile
#define TC (TX + 6)   // 70 cols used
#define TSX (TX + 8)  // LDS row stride (72 floats) to keep rows 8-aligned

__global__ __launch_bounds__(256) void open_kernel(const float* __restrict__ mask,
                                                   float* __restrict__ out) {
    __shared__ float s_a[TR][TSX];
    __shared__ float s_b[TR][TSX];
    const int tid = threadIdx.x;
    const int gx0 = blockIdx.x * TX;
    const int gy0 = blockIdx.y * TY;
    const int b   = blockIdx.z;
    const float* img  = mask + (size_t)b * H * W;
    float*       outp = out  + (size_t)b * H * W;

    // Phase 1: global load + threshold into s_a.
    // LDS row r <-> global row gy0 + r - 3; col c <-> global col gx0 + c - 3.
    // OOB = +inf (erosion identity).
    for (int idx = tid; idx < TR * TC; idx += 256) {
        int r = idx / TC, c = idx - r * TC;
        int gy = gy0 + r - 3, gx = gx0 + c - 3;
        float v;
        if (gy >= 0 && gy < H && gx >= 0 && gx < W) {
            float m = img[gy * W + gx];
            v = (m >= 0.5f) ? m : 0.0f;
        } else {
            v = INFINITY;
        }
        s_a[r][c] = v;
    }
    __syncthreads();

    // Phase 2: horizontal min (window x-2..x+1) -> s_b.
    // Need cols j in [-1, TX+1] (67 values, c in [2,68]) for all 70 rows.
    for (int idx = tid; idx < TR * 67; idx += 256) {
        int r = idx / 67, c = idx - r * 67 + 2;
        float v = fminf(fminf(s_a[r][c - 2], s_a[r][c - 1]),
                        fminf(s_a[r][c],     s_a[r][c + 1]));
        s_b[r][c] = v;
    }
    __syncthreads();

    // Phase 3: vertical min (window y-2..y+1) -> eroded, into s_a.
    // Need rows i in [-1, TY+1] (r in [2,68]), cols j in [-1, TX+1] (c in [2,68]).
    // Eroded values at globally-OOB positions don't exist -> -inf (dilation identity).
    for (int idx = tid; idx < 67 * 67; idx += 256) {
        int rr = idx / 67, cc = idx - rr * 67;
        int r = rr + 2, c = cc + 2;
        float v = fminf(fminf(s_b[r - 2][c], s_b[r - 1][c]),
                        fminf(s_b[r][c],     s_b[r + 1][c]));
        int gy = gy0 + r - 3, gx = gx0 + c - 3;
        if (gy < 0 || gy >= H || gx < 0 || gx >= W) v = -INFINITY;
        s_a[r][c] = v;
    }
    __syncthreads();

    // Phase 4: horizontal max (window x-1..x+2) -> s_b.
    // Need cols j in [0, TX-1] (c in [3,66]), rows i in [-1, TY+1] (r in [2,68]).
    for (int idx = tid; idx < 67 * TX; idx += 256) {
        int r = idx / TX + 2, c = (idx & (TX - 1)) + 3;
        float v = fmaxf(fmaxf(s_a[r][c - 1], s_a[r][c]),
                        fmaxf(s_a[r][c + 1], s_a[r][c + 2]));
        s_b[r][c] = v;
    }
    __syncthreads();

    // Phase 5: vertical max (window y-1..y+2) + coalesced store.
    for (int idx = tid; idx < TY * TX; idx += 256) {
        int i = idx / TX, j = idx & (TX - 1);
        int r = i + 3, c = j + 3;
        float v = fmaxf(fmaxf(s_b[r - 1][c], s_b[r][c]),
                        fmaxf(s_b[r + 1][c], s_b[r + 2][c]));
        outp[(gy0 + i) * W + (gx0 + j)] = v;
    }
}

__global__ __launch_bounds__(256) void score_kernel(const float* __restrict__ s,
                                                    float* __restrict__ out, int n) {
    int i = blockIdx.x * 256 + threadIdx.x;
    if (i < n) {
        float v = s[i];
        out[i] = (v >= 0.5f) ? v : 0.0f;
    }
}

extern "C" void kernel_launch(void* const* d_in, const int* in_sizes, int n_in,
                              void* d_out, int out_size, void* d_ws, size_t ws_size,
                              hipStream_t stream) {
    const float* score = (const float*)d_in[0];
    const float* mask  = (const float*)d_in[1];
    float* out = (float*)d_out;

    const int n_score = in_sizes[0];              // 32 * 1000
    const int batch   = in_sizes[1] / (H * W);    // 32

    score_kernel<<<(n_score + 255) / 256, 256, 0, stream>>>(score, out, n_score);

    dim3 grid(W / TX, H / TY, batch);
    open_kernel<<<grid, 256, 0, stream>>>(mask, out + n_score);
}

// Round 2
// 262.116 us; speedup vs baseline: 1.2703x; 1.2703x over previous
//
#include <hip/hip_runtime.h>
#include <math.h>

// FilterDetection: score threshold + morphological opening (erode 4x4,
// dilate 4x4) on 32x1024x1024 f32.
//
// Register-streaming design: no LDS, no barriers. Each lane owns 4 consecutive
// columns and streams down rows. Per row it loads 3 aligned float4s
// (cols c0-4..c0+7), thresholds, computes horizontal min for 8 cols
// (c0-2..c0+5) in registers, maintains a 4-row sliding window of those
// (vertical erosion), masks OOB to -inf, computes horizontal max for its 4
// cols, maintains a 4-row sliding window of hmax (vertical dilation), and
// stores one float4. Redundant neighbor loads are same-wave L1 hits.
//
// Window geometry (from lax.reduce_window padding):
//   erode : offsets [-2..+1] both axes, OOB = +inf
//   dilate: offsets [-1..+2] both axes, OOB = -inf

#define H 1024
#define W 1024
#define R 32                        // rows per strip
#define STRIPS (H / R)
#define BATCH 32
#define MASK_BLOCKS (STRIPS * BATCH)
#define N_SCORE 32000
#define SCORE_BLOCKS ((N_SCORE + 255) / 256)

__device__ __forceinline__ float th(float v) { return v >= 0.5f ? v : 0.0f; }

__global__ __launch_bounds__(256) void fused_kernel(const float* __restrict__ score,
                                                    const float* __restrict__ mask,
                                                    float* __restrict__ out) {
    const int bid = blockIdx.x;
    const int tid = threadIdx.x;

    if (bid >= MASK_BLOCKS) {               // tail blocks: score threshold
        int i = (bid - MASK_BLOCKS) * 256 + tid;
        if (i < N_SCORE) out[i] = th(score[i]);
        return;
    }

    const int b     = bid / STRIPS;
    const int strip = bid % STRIPS;
    const int y0    = strip * R;
    const int wave  = tid >> 6;
    const int lane  = tid & 63;
    const int c0    = wave * 256 + lane * 4;   // first of this lane's 4 columns

    const float* img  = mask + (size_t)b * (H * W);
    float*       outp = out + N_SCORE + (size_t)b * (H * W);

    const bool okL = (c0 >= 4);        // prev float4 (cols c0-4..c0-1) in bounds
    const bool okR = (c0 + 7 < W);     // next float4 (cols c0+4..c0+7) in bounds

    // e-column validity for cols c0-2+k (k=0..7)
    bool colok[8];
    #pragma unroll
    for (int k = 0; k < 8; ++k) {
        int col = c0 - 2 + k;
        colok[k] = (col >= 0) && (col < W);
    }

    float hmw[4][8];   // hmin rows t-3..t (0 = oldest), cols c0-2..c0+5
    float hxw[4][4];   // hmax rows (t-1)-3..(t-1), cols c0..c0+3
    #pragma unroll
    for (int i = 0; i < 4; ++i) {
        #pragma unroll
        for (int k = 0; k < 8; ++k) hmw[i][k] = INFINITY;
        #pragma unroll
        for (int k = 0; k < 4; ++k) hxw[i][k] = -INFINITY;
    }

    const float4 inf4 = make_float4(INFINITY, INFINITY, INFINITY, INFINITY);

    #pragma unroll 2
    for (int it = 0; it < R + 6; ++it) {
        const int t = y0 - 3 + it;     // input row being consumed

        // ---- load + threshold input cols c0-4..c0+7 (OOB -> +inf) ----
        float a[12];
        if (t >= 0 && t < H) {
            const float4* rowp = (const float4*)(img + (size_t)t * W + c0);
            float4 pv = okL ? rowp[-1] : inf4;
            float4 cv = rowp[0];
            float4 nv = okR ? rowp[1] : inf4;
            a[0] = th(pv.x); a[1] = th(pv.y); a[2]  = th(pv.z); a[3]  = th(pv.w);
            a[4] = th(cv.x); a[5] = th(cv.y); a[6]  = th(cv.z); a[7]  = th(cv.w);
            a[8] = th(nv.x); a[9] = th(nv.y); a[10] = th(nv.z); a[11] = th(nv.w);
        } else {
            #pragma unroll
            for (int k = 0; k < 12; ++k) a[k] = INFINITY;
        }

        // ---- shift hmin window; hm(t) for cols c0-2+k needs a[k..k+3] ----
        #pragma unroll
        for (int i = 0; i < 3; ++i)
            #pragma unroll
            for (int k = 0; k < 8; ++k) hmw[i][k] = hmw[i + 1][k];
        #pragma unroll
        for (int k = 0; k < 8; ++k)
            hmw[3][k] = fminf(fminf(a[k], a[k + 1]), fminf(a[k + 2], a[k + 3]));

        // ---- eroded row r = t-1: vertical min of hmw; OOB row/col -> -inf ----
        const int r = t - 1;
        const bool rowok = (r >= 0) && (r < H);
        float ec[8];
        #pragma unroll
        for (int k = 0; k < 8; ++k) {
            float e = fminf(fminf(hmw[0][k], hmw[1][k]), fminf(hmw[2][k], hmw[3][k]));
            ec[k] = (rowok && colok[k]) ? e : -INFINITY;
        }

        // ---- shift hmax window; hx(r) at col c0+j needs ec[j+1..j+4] ----
        #pragma unroll
        for (int i = 0; i < 3; ++i)
            #pragma unroll
            for (int k = 0; k < 4; ++k) hxw[i][k] = hxw[i + 1][k];
        #pragma unroll
        for (int j = 0; j < 4; ++j)
            hxw[3][j] = fmaxf(fmaxf(ec[j + 1], ec[j + 2]), fmaxf(ec[j + 3], ec[j + 4]));

        // ---- output row y = t-3 = vertical max of hxw (hx rows y-1..y+2) ----
        const int y = t - 3;
        if (y >= y0) {
            float4 o;
            o.x = fmaxf(fmaxf(hxw[0][0], hxw[1][0]), fmaxf(hxw[2][0], hxw[3][0]));
            o.y = fmaxf(fmaxf(hxw[0][1], hxw[1][1]), fmaxf(hxw[2][1], hxw[3][1]));
            o.z = fmaxf(fmaxf(hxw[0][2], hxw[1][2]), fmaxf(hxw[2][2], hxw[3][2]));
            o.w = fmaxf(fmaxf(hxw[0][3], hxw[1][3]), fmaxf(hxw[2][3], hxw[3][3]));
            *(float4*)(outp + (size_t)y * W + c0) = o;
        }
    }
}

extern "C" void kernel_launch(void* const* d_in, const int* in_sizes, int n_in,
                              void* d_out, int out_size, void* d_ws, size_t ws_size,
                              hipStream_t stream) {
    const float* score = (const float*)d_in[0];
    const float* mask  = (const float*)d_in[1];
    float* out = (float*)d_out;

    const int grid = MASK_BLOCKS + SCORE_BLOCKS;
    fused_kernel<<<grid, 256, 0, stream>>>(score, mask, out);
}

// Round 3
// 262.018 us; speedup vs baseline: 1.2708x; 1.0004x over previous
//
#include <hip/hip_runtime.h>
#include <math.h>

// FilterDetection: score threshold + morphological opening (erode 4x4,
// dilate 4x4) on 32x1024x1024 f32.
//
// Register-streaming, no LDS/barriers. Each lane owns 4 consecutive columns,
// streams down a 16-row strip. Per row: 3 aligned float4 loads (prev/cur/next,
// neighbors are L1 hits), horizontal min in regs, 4-row sliding vertical min,
// OOB fold to -inf, horizontal max, 4-row sliding vertical max, float4 store.
//
// Threshold is DEFERRED to the store: th(x)= x>=0.5?x:0 is monotone, and
// min/max commute with monotone maps (th(+inf)=+inf so the erosion pad is
// preserved; the -inf dilation pad never wins because the dilation window
// always contains the in-bounds pixel itself, whose eroded value is finite).
// So th(dilate(erode(m))) == dilate(erode(th(m))) exactly.
//
// Latency hiding: explicit prefetch of row t+1 before computing row t, plus
// R=16 strips -> 2048 mask blocks (~8.5 blocks/CU).
//
// Window geometry (from lax.reduce_window padding):
//   erode : offsets [-2..+1] both axes, OOB = +inf
//   dilate: offsets [-1..+2] both axes, OOB = -inf

#define H 1024
#define W 1024
#define R 16                         // rows per strip
#define STRIPS (H / R)               // 64
#define BATCH 32
#define MASK_BLOCKS (STRIPS * BATCH) // 2048
#define N_SCORE 32000
#define SCORE_BLOCKS ((N_SCORE + 255) / 256)

__device__ __forceinline__ float th(float v) { return v >= 0.5f ? v : 0.0f; }

__global__ __launch_bounds__(256, 4)
void fused_kernel(const float* __restrict__ score,
                  const float* __restrict__ mask,
                  float* __restrict__ out) {
    const int bid = blockIdx.x;
    const int tid = threadIdx.x;

    if (bid >= MASK_BLOCKS) {               // tail blocks: score threshold
        int i = (bid - MASK_BLOCKS) * 256 + tid;
        if (i < N_SCORE) out[i] = th(score[i]);
        return;
    }

    const int b     = bid >> 6;             // / STRIPS
    const int strip = bid & (STRIPS - 1);
    const int y0    = strip * R;
    const int c0    = ((tid >> 6) << 8) + (tid & 63) * 4;  // first owned column

    const float* img  = mask + (size_t)b * (H * W);
    float*       outp = out + N_SCORE + (size_t)b * (H * W);

    const bool okL = (c0 >= 4);
    const bool okR = (c0 + 7 < W);

    // Column limit for eroded cols c0-2+k: +inf keeps value, -inf forces pad.
    float cm[8];
    #pragma unroll
    for (int k = 0; k < 8; ++k) {
        int col = c0 - 2 + k;
        cm[k] = (col >= 0 && col < W) ? INFINITY : -INFINITY;
    }

    float hmw[4][8];   // hmin rows t-3..t (0 = oldest), cols c0-2..c0+5
    float hxw[4][4];   // hmax rows t-4..t-1, cols c0..c0+3
    #pragma unroll
    for (int i = 0; i < 4; ++i) {
        #pragma unroll
        for (int k = 0; k < 8; ++k) hmw[i][k] = INFINITY;
        #pragma unroll
        for (int k = 0; k < 4; ++k) hxw[i][k] = -INFINITY;
    }

    const float4 inf4 = make_float4(INFINITY, INFINITY, INFINITY, INFINITY);

    // Prefetch state: raw (unthresholded) row t.
    float4 Pp, Pc, Pn;
    {
        const int t = y0 - 3;
        if (t >= 0) {   // t < H always holds here
            const float4* rowp = (const float4*)(img + (size_t)t * W + c0);
            Pp = okL ? rowp[-1] : inf4;
            Pc = rowp[0];
            Pn = okR ? rowp[1] : inf4;
        } else {
            Pp = Pc = Pn = inf4;
        }
    }

    #pragma unroll 2
    for (int it = 0; it < R + 6; ++it) {
        const int t = y0 - 3 + it;          // row consumed this iteration

        float a[12];
        a[0] = Pp.x; a[1] = Pp.y; a[2]  = Pp.z; a[3]  = Pp.w;
        a[4] = Pc.x; a[5] = Pc.y; a[6]  = Pc.z; a[7]  = Pc.w;
        a[8] = Pn.x; a[9] = Pn.y; a[10] = Pn.z; a[11] = Pn.w;

        // Prefetch row t+1 (always; OOB -> +inf). Loads retire during compute.
        {
            const int tn = t + 1;
            if (tn >= 0 && tn < H) {
                const float4* rowp = (const float4*)(img + (size_t)tn * W + c0);
                Pp = okL ? rowp[-1] : inf4;
                Pc = rowp[0];
                Pn = okR ? rowp[1] : inf4;
            } else {
                Pp = Pc = Pn = inf4;
            }
        }

        // Horizontal min for row t, cols c0-2+k: window a[k..k+3].
        #pragma unroll
        for (int i = 0; i < 3; ++i)
            #pragma unroll
            for (int k = 0; k < 8; ++k) hmw[i][k] = hmw[i + 1][k];
        #pragma unroll
        for (int k = 0; k < 8; ++k)
            hmw[3][k] = fminf(fminf(a[k], a[k + 1]), fminf(a[k + 2], a[k + 3]));

        // Eroded row r = t-1 (vertical min over rows r-2..r+1 = t-3..t),
        // folded with row/col OOB -> -inf (dilation pad).
        const int r = t - 1;
        const float rlim = (r >= 0 && r < H) ? INFINITY : -INFINITY;  // uniform
        float ec[8];
        #pragma unroll
        for (int k = 0; k < 8; ++k) {
            float e = fminf(fminf(hmw[0][k], hmw[1][k]),
                            fminf(hmw[2][k], hmw[3][k]));
            ec[k] = fminf(fminf(e, cm[k]), rlim);
        }

        // Horizontal max for eroded row r, col c0+j: window ec[j+1..j+4].
        #pragma unroll
        for (int i = 0; i < 3; ++i)
            #pragma unroll
            for (int k = 0; k < 4; ++k) hxw[i][k] = hxw[i + 1][k];
        #pragma unroll
        for (int j = 0; j < 4; ++j)
            hxw[3][j] = fmaxf(fmaxf(ec[j + 1], ec[j + 2]),
                              fmaxf(ec[j + 3], ec[j + 4]));

        // Output row y = t-3 (vertical max over hx rows y-1..y+2), thresholded.
        const int y = t - 3;
        if (y >= y0) {
            float4 o;
            o.x = th(fmaxf(fmaxf(hxw[0][0], hxw[1][0]), fmaxf(hxw[2][0], hxw[3][0])));
            o.y = th(fmaxf(fmaxf(hxw[0][1], hxw[1][1]), fmaxf(hxw[2][1], hxw[3][1])));
            o.z = th(fmaxf(fmaxf(hxw[0][2], hxw[1][2]), fmaxf(hxw[2][2], hxw[3][2])));
            o.w = th(fmaxf(fmaxf(hxw[0][3], hxw[1][3]), fmaxf(hxw[2][3], hxw[3][3])));
            *(float4*)(outp + (size_t)y * W + c0) = o;
        }
    }
}

extern "C" void kernel_launch(void* const* d_in, const int* in_sizes, int n_in,
                              void* d_out, int out_size, void* d_ws, size_t ws_size,
                              hipStream_t stream) {
    const float* score = (const float*)d_in[0];
    const float* mask  = (const float*)d_in[1];
    float* out = (float*)d_out;

    const int grid = MASK_BLOCKS + SCORE_BLOCKS;
    fused_kernel<<<grid, 256, 0, stream>>>(score, mask, out);
}

// Round 7
// 258.994 us; speedup vs baseline: 1.2856x; 1.0117x over previous
//
#include <hip/hip_runtime.h>
#include <math.h>

// FilterDetection: score threshold + morphological opening (erode 4x4,
// dilate 4x4) on 32x1024x1024 f32.
//
// Register-streaming, no LDS/barriers. Each lane owns 4 consecutive columns,
// streams down a 16-row strip. Per row: 3 aligned float4 loads (prev/cur/next;
// neighbors are L1 hits), horizontal min in regs, 4-row sliding vertical min,
// OOB fold to -inf, horizontal max, 4-row sliding vertical max, float4 store.
//
// Threshold deferred to the store (min/max commute with the monotone th();
// th(+inf)=+inf preserves the erosion pad; the -inf dilation pad never wins
// for in-bounds outputs). Verified absmax=0 in rounds 1-3.
//
// Latency: software-pipelined register FIFO of depth 3 (rows t+1..t+3 in
// flight) + FULL unroll of the 22-iteration loop so the FIFO and sliding
// windows become SSA and the compiler emits fine-grained vmcnt(N) waits.
//
// BUG HISTORY (rounds 5-6): store guard `it >= 3` wrote rows y0-3..y0-1
// (previous strip's rows); row y0-3 lacked the hx(y0-4) contribution and
// raced with the neighbor block's correct write -> nondeterministic replay
// failures. Correct guard: it >= 6 (y = y0-6+it >= y0). Output rows must
// stay strictly within the strip.
//
// Window geometry (from lax.reduce_window padding):
//   erode : offsets [-2..+1] both axes, OOB = +inf
//   dilate: offsets [-1..+2] both axes, OOB = -inf

#define H 1024
#define W 1024
#define R 16                         // rows per strip
#define STRIPS (H / R)               // 64
#define BATCH 32
#define MASK_BLOCKS (STRIPS * BATCH) // 2048
#define N_SCORE 32000
#define SCORE_BLOCKS ((N_SCORE + 255) / 256)

__device__ __forceinline__ float th(float v) { return v >= 0.5f ? v : 0.0f; }

__global__ __launch_bounds__(256, 4)
void fused_kernel(const float* __restrict__ score,
                  const float* __restrict__ mask,
                  float* __restrict__ out) {
    const int bid = blockIdx.x;
    const int tid = threadIdx.x;

    if (bid >= MASK_BLOCKS) {               // tail blocks: score threshold
        int i = (bid - MASK_BLOCKS) * 256 + tid;
        if (i < N_SCORE) out[i] = th(score[i]);
        return;
    }

    const int b     = bid >> 6;             // / STRIPS
    const int strip = bid & (STRIPS - 1);
    const int y0    = strip * R;
    const int c0    = ((tid >> 6) << 8) + (tid & 63) * 4;  // first owned column

    const float* img  = mask + (size_t)b * (H * W);
    float*       outp = out + N_SCORE + (size_t)b * (H * W);

    const bool okL = (c0 >= 4);
    const bool okR = (c0 + 7 < W);

    // Column limit for eroded cols c0-2+k: +inf keeps value, -inf forces pad.
    float cm[8];
    #pragma unroll
    for (int k = 0; k < 8; ++k) {
        int col = c0 - 2 + k;
        cm[k] = (col >= 0 && col < W) ? INFINITY : -INFINITY;
    }

    float hmw[4][8];   // hmin rows t-3..t (0 = oldest), cols c0-2..c0+5
    float hxw[4][4];   // hmax rows t-4..t-1, cols c0..c0+3
    #pragma unroll
    for (int i = 0; i < 4; ++i) {
        #pragma unroll
        for (int k = 0; k < 8; ++k) hmw[i][k] = INFINITY;
        #pragma unroll
        for (int k = 0; k < 4; ++k) hxw[i][k] = -INFINITY;
    }

    const float4 inf4 = make_float4(INFINITY, INFINITY, INFINITY, INFINITY);

    // Depth-3 register FIFO of raw rows. Slot d holds row t where t%3 == phase.
    float4 Fp[3], Fc[3], Fn[3];

    // Prologue: rows y0-3 .. y0-1 into slots 0..2.
    #pragma unroll
    for (int d = 0; d < 3; ++d) {
        const int ty = y0 - 3 + d;
        if (ty >= 0) {                       // ty < H always (y0 <= H-R)
            const float4* rowp = (const float4*)(img + (size_t)ty * W + c0);
            Fp[d] = okL ? rowp[-1] : inf4;
            Fc[d] = rowp[0];
            Fn[d] = okR ? rowp[1] : inf4;
        } else {
            Fp[d] = Fc[d] = Fn[d] = inf4;
        }
    }

    #pragma unroll
    for (int it = 0; it < R + 6; ++it) {
        const int t = y0 - 3 + it;          // row consumed this iteration
        const int s = it % 3;               // FIFO slot (compile-time)

        float a[12];
        a[0] = Fp[s].x; a[1] = Fp[s].y; a[2]  = Fp[s].z; a[3]  = Fp[s].w;
        a[4] = Fc[s].x; a[5] = Fc[s].y; a[6]  = Fc[s].z; a[7]  = Fc[s].w;
        a[8] = Fn[s].x; a[9] = Fn[s].y; a[10] = Fn[s].z; a[11] = Fn[s].w;

        // Refill slot s with row t+3 (consumed at iteration it+3).
        if (it < R + 3) {
            const int tn = t + 3;           // == y0 + it, always >= 0
            if (tn < H) {
                const float4* rowp = (const float4*)(img + (size_t)tn * W + c0);
                Fp[s] = okL ? rowp[-1] : inf4;
                Fc[s] = rowp[0];
                Fn[s] = okR ? rowp[1] : inf4;
            } else {
                Fp[s] = Fc[s] = Fn[s] = inf4;
            }
        }

        // Horizontal min for row t, cols c0-2+k: window a[k..k+3].
        #pragma unroll
        for (int i = 0; i < 3; ++i)
            #pragma unroll
            for (int k = 0; k < 8; ++k) hmw[i][k] = hmw[i + 1][k];
        #pragma unroll
        for (int k = 0; k < 8; ++k)
            hmw[3][k] = fminf(fminf(a[k], a[k + 1]), fminf(a[k + 2], a[k + 3]));

        // Eroded row r = t-1 (vertical min over rows t-3..t), folded with
        // row/col OOB -> -inf (dilation pad).
        const int r = t - 1;
        const float rlim = (r >= 0 && r < H) ? INFINITY : -INFINITY;  // uniform
        float ec[8];
        #pragma unroll
        for (int k = 0; k < 8; ++k) {
            float e = fminf(fminf(hmw[0][k], hmw[1][k]),
                            fminf(hmw[2][k], hmw[3][k]));
            ec[k] = fminf(fminf(e, cm[k]), rlim);
        }

        // Horizontal max for eroded row r, col c0+j: window ec[j+1..j+4].
        #pragma unroll
        for (int i = 0; i < 3; ++i)
            #pragma unroll
            for (int k = 0; k < 4; ++k) hxw[i][k] = hxw[i + 1][k];
        #pragma unroll
        for (int j = 0; j < 4; ++j)
            hxw[3][j] = fmaxf(fmaxf(ec[j + 1], ec[j + 2]),
                              fmaxf(ec[j + 3], ec[j + 4]));

        // Output row y = t-3 = y0-6+it (vertical max over hx rows y-1..y+2),
        // thresholded. Guard it>=6 keeps writes strictly inside the strip.
        if (it >= 6) {
            const int y = t - 3;
            float4 o;
            o.x = th(fmaxf(fmaxf(hxw[0][0], hxw[1][0]), fmaxf(hxw[2][0], hxw[3][0])));
            o.y = th(fmaxf(fmaxf(hxw[0][1], hxw[1][1]), fmaxf(hxw[2][1], hxw[3][1])));
            o.z = th(fmaxf(fmaxf(hxw[0][2], hxw[1][2]), fmaxf(hxw[2][2], hxw[3][2])));
            o.w = th(fmaxf(fmaxf(hxw[0][3], hxw[1][3]), fmaxf(hxw[2][3], hxw[3][3])));
            *(float4*)(outp + (size_t)y * W + c0) = o;
        }
    }
}

extern "C" void kernel_launch(void* const* d_in, const int* in_sizes, int n_in,
                              void* d_out, int out_size, void* d_ws, size_t ws_size,
                              hipStream_t stream) {
    const float* score = (const float*)d_in[0];
    const float* mask  = (const float*)d_in[1];
    float* out = (float*)d_out;

    const int grid = MASK_BLOCKS + SCORE_BLOCKS;
    fused_kernel<<<grid, 256, 0, stream>>>(score, mask, out);
}

// Round 8
// 245.998 us; speedup vs baseline: 1.3535x; 1.0528x over previous
//
#include <hip/hip_runtime.h>
#include <math.h>

// FilterDetection: score threshold + morphological opening (erode 4x4,
// dilate 4x4) on 32x1024x1024 f32.
//
// Round-8 design: 8 columns per lane, one wave = one full 512-col segment of
// a 16-row strip. Per row each lane does 4 unaligned (dword-aligned) vector
// loads covering raw cols c0-3..c0+10 (14 floats) -> computes hmin for 11
// cols, sliding 4-row vertical min (3 history rows), OOB fold to -inf,
// hmax for its 8 cols, sliding 4-row vertical max, 2x float4 store.
// No LDS, no barriers, no cross-lane ops; image-edge lanes handled by
// address clamp + per-lane-constant selects (no divergent control flow).
//
// Rationale (rounds 2-7 post-mortems): dur was pinned at ~102us across three
// structurally different 4-col variants; VALUBusy<34%, occupancy<=50% ->
// per-wave latency serialization. This round: 8-wide per-lane ILP (~170
// independent VALU/row) x 4 waves/SIMD resident (1024 blocks = 4/CU,
// VGPR<=128 via __launch_bounds__(256,4)) to cover miss latency with issue.
//
// Threshold deferred to store (monotone th() commutes with min/max; verified
// absmax=0 rounds 1-7). Store guard keeps writes strictly inside the strip
// (round-6 race bug). Plain coherent stores only (round-5 nt-store hazard).
//
// Window geometry (from lax.reduce_window padding):
//   erode : offsets [-2..+1] both axes, OOB = +inf
//   dilate: offsets [-1..+2] both axes, OOB = -inf
// Output col j needs raw cols j-3..j+3; eroded values at OOB cols/rows are
// -inf (dilation pad), raw OOB values are +inf (erosion pad).

#define H 1024
#define W 1024
#define R 16
#define STRIPS (H / R)                    // 64
#define SEGS 2                            // 512-col segments per row
#define BATCH 32
#define TASKS (STRIPS * SEGS * BATCH)     // 4096 wave-tasks
#define MASK_BLOCKS (TASKS / 4)           // 1024 blocks, 4 waves each
#define N_SCORE 32000
#define SCORE_BLOCKS ((N_SCORE + 255) / 256)

__device__ __forceinline__ float th(float v) { return v >= 0.5f ? v : 0.0f; }

__global__ __launch_bounds__(256, 4)
void fused_kernel(const float* __restrict__ score,
                  const float* __restrict__ mask,
                  float* __restrict__ out) {
    const int bid = blockIdx.x;
    const int tid = threadIdx.x;

    if (bid >= MASK_BLOCKS) {               // tail blocks: score threshold
        int i = (bid - MASK_BLOCKS) * 256 + tid;
        if (i < N_SCORE) out[i] = th(score[i]);
        return;
    }

    const int wave = tid >> 6;
    const int lane = tid & 63;
    const int task = bid * 4 + wave;        // one wave = one (img,strip,seg)
    const int b    = task >> 7;             // 128 tasks per image
    const int rem  = task & 127;
    const int strip= rem >> 1;
    const int seg  = rem & 1;
    const int y0   = strip * R;
    const int c0   = seg * 512 + lane * 8;  // first of this lane's 8 columns

    const float* img  = mask + (size_t)b * (H * W);
    float*       outp = out + N_SCORE + (size_t)b * (H * W);

    const bool eL = (c0 == 0);              // needs cols < 0 (pad)
    const bool eR = (c0 == W - 8);          // needs cols >= W (pad)
    // Clamped load offsets (floats), all guaranteed in [0, W-4]/[0, W-2]:
    const int o0 = eL ? 0       : (c0 - 3); // raw cols c0-3..c0   (4)
    const int o1 = c0 + 1;                  // raw cols c0+1..c0+4 (4)
    const int o2 = eR ? (W - 4) : (c0 + 5); // raw cols c0+5..c0+8 (4)
    const int o3 = eR ? (W - 2) : (c0 + 9); // raw cols c0+9..c0+10 (2)

    // Eroded-col mask for ec index m (col c0-1+m): +inf keeps, -inf pads.
    float cm[11];
    #pragma unroll
    for (int m = 0; m < 11; ++m) {
        int col = c0 - 1 + m;
        cm[m] = (col >= 0 && col < W) ? INFINITY : -INFINITY;
    }

    // Sliding windows: 3 history rows + current.
    float hmw0[11], hmw1[11], hmw2[11];     // hmin rows t-1, t-2, t-3
    float hxw0[8],  hxw1[8],  hxw2[8];      // hmax rows r-1, r-2, r-3
    #pragma unroll
    for (int m = 0; m < 11; ++m) { hmw0[m] = hmw1[m] = hmw2[m] = INFINITY; }
    #pragma unroll
    for (int j = 0; j < 8; ++j)  { hxw0[j] = hxw1[j] = hxw2[j] = -INFINITY; }

    #pragma unroll
    for (int it = 0; it < R + 6; ++it) {
        const int t = y0 - 3 + it;          // raw row consumed this iteration

        // ---- load raw cols c0-3..c0+10 into ar[0..13] (OOB -> +inf) ----
        float ar[14];
        if (t >= 0 && t < H) {
            const float* row = img + (size_t)t * W;
            float4 L0, L1, L2; float2 L3;
            __builtin_memcpy(&L0, row + o0, 16);   // dword-aligned dwordx4
            __builtin_memcpy(&L1, row + o1, 16);
            __builtin_memcpy(&L2, row + o2, 16);
            __builtin_memcpy(&L3, row + o3, 8);
            ar[0]  = eL ? INFINITY : L0.x;   // col c0-3
            ar[1]  = eL ? INFINITY : L0.y;   // col c0-2
            ar[2]  = eL ? INFINITY : L0.z;   // col c0-1
            ar[3]  = eL ? L0.x     : L0.w;   // col c0
            ar[4]  = L1.x;  ar[5] = L1.y;  ar[6] = L1.z;  ar[7] = L1.w;
            ar[8]  = eR ? L2.y : L2.x;       // col c0+5
            ar[9]  = eR ? L2.z : L2.y;       // col c0+6
            ar[10] = eR ? L2.w : L2.z;       // col c0+7
            ar[11] = eR ? INFINITY : L2.w;   // col c0+8
            ar[12] = eR ? INFINITY : L3.x;   // col c0+9
            ar[13] = eR ? INFINITY : L3.y;   // col c0+10
        } else {
            #pragma unroll
            for (int k = 0; k < 14; ++k) ar[k] = INFINITY;
        }

        // ---- hmin row t for cols c0-1+m (m=0..10): raw window ar[m..m+3] ----
        float hm[11];
        #pragma unroll
        for (int m = 0; m < 11; ++m)
            hm[m] = fminf(fminf(ar[m], ar[m + 1]), fminf(ar[m + 2], ar[m + 3]));

        // ---- eroded row r = t-1: vertical min rows t-3..t, OOB -> -inf ----
        const int r = t - 1;
        const float rlim = (r >= 0 && r < H) ? INFINITY : -INFINITY;  // uniform
        float ec[11];
        #pragma unroll
        for (int m = 0; m < 11; ++m) {
            float e = fminf(fminf(hmw2[m], hmw1[m]), fminf(hmw0[m], hm[m]));
            ec[m] = fminf(fminf(e, cm[m]), rlim);
        }

        // shift hmin history (renamed under full unroll)
        #pragma unroll
        for (int m = 0; m < 11; ++m) { hmw2[m] = hmw1[m]; hmw1[m] = hmw0[m]; hmw0[m] = hm[m]; }

        // ---- hmax row r, col c0+j: eroded window ec[j..j+3] ----
        float hx[8];
        #pragma unroll
        for (int j = 0; j < 8; ++j)
            hx[j] = fmaxf(fmaxf(ec[j], ec[j + 1]), fmaxf(ec[j + 2], ec[j + 3]));

        // ---- output row y = t-3 = y0-6+it: vertical max hx rows y-1..y+2 ----
        if (it >= 6) {                       // strictly inside the strip
            const int y = t - 3;
            float o[8];
            #pragma unroll
            for (int j = 0; j < 8; ++j)
                o[j] = th(fmaxf(fmaxf(hxw2[j], hxw1[j]), fmaxf(hxw0[j], hx[j])));
            float* po = outp + (size_t)y * W + c0;
            float4 s0 = make_float4(o[0], o[1], o[2], o[3]);
            float4 s1 = make_float4(o[4], o[5], o[6], o[7]);
            *(float4*)(po)     = s0;
            *(float4*)(po + 4) = s1;
        }

        // shift hmax history
        #pragma unroll
        for (int j = 0; j < 8; ++j) { hxw2[j] = hxw1[j]; hxw1[j] = hxw0[j]; hxw0[j] = hx[j]; }
    }
}

extern "C" void kernel_launch(void* const* d_in, const int* in_sizes, int n_in,
                              void* d_out, int out_size, void* d_ws, size_t ws_size,
                              hipStream_t stream) {
    const float* score = (const float*)d_in[0];
    const float* mask  = (const float*)d_in[1];
    float* out = (float*)d_out;

    const int grid = MASK_BLOCKS + SCORE_BLOCKS;
    fused_kernel<<<grid, 256, 0, stream>>>(score, mask, out);
}